// Round 1
// baseline (101.873 us; speedup 1.0000x reference)
//
#include <hip/hip_runtime.h>
#include <cstdint>

// RNN: B=8192, T=2048, I=1, H=2, O=1. One thread per batch element.
//
// R3: (a) truncated fading-memory scan with relaxed target sigma^K <= 1e-3
// (rigorous worst-case output error <= sqrt(2)*sigma^K = 1.4e-3, 6x under
// the 8.75e-3 threshold); (b) 5-op dependent chain via r-state:
//   r = rcp(exp2(u) + 0.5),  h = 1 - r,  u = z - 1 (z = 2*log2e * prezact)
// so the next step's u' = sg' - A00*r0 - A01*r1 with all constants
// (S*(b_ih+b_hh) + S*W_hh.rowsum - 1) folded into sc. Chain per step:
// fma, fma, exp2, add, rcp  (was 6 ops with the h-state form).
//
// R4: extend truncation to the K > 256 regime. Previously 256 < K < len
// fell back to the FULL exact scan (~2040 steps); absmax=0.0 on the last
// bench proves that fallback was the active path (bit-exact output), i.e.
// K > 256 for this seed. Now the fallback starts the exact scan at
// start = max(0, (len-K) & ~31) with h = 0: same float4 32-step pipeline,
// same rigorous error bound sigma^(len-start) <= sigma^K <= 1e-3, but only
// K+<=31 steps instead of len. K >= len (sigma ~> 0.9966) degenerates to
// start = 0, identical to the old full scan.
//
// Masked prefix (fast path, t < 0 for lanes with len < Kp): force sg to the
// constant (A00+A01-1) off the critical path -> u = -1 -> exp2 = 0.5
// -> d = 1.0 -> r = 1.0 (all exact), i.e. h stays exactly 0.

#define T_LEN 2048

__device__ __forceinline__ float fast_exp2(float x) {
#if __has_builtin(__builtin_amdgcn_exp2f)
  return __builtin_amdgcn_exp2f(x);
#else
  return exp2f(x);
#endif
}

__device__ __forceinline__ float fast_rcp(float x) {
#if __has_builtin(__builtin_amdgcn_rcpf)
  return __builtin_amdgcn_rcpf(x);
#else
  return 1.0f / x;
#endif
}

// One step in r-state. sg already includes the +rowsum-1 constant fold.
__device__ __forceinline__ void rnn_step_r(float sg0, float sg1,
                                           float A00, float A01,
                                           float A10, float A11,
                                           float& r0, float& r1) {
  float u0 = fmaf(-A00, r0, fmaf(-A01, r1, sg0));
  float u1 = fmaf(-A10, r0, fmaf(-A11, r1, sg1));
  float e0 = fast_exp2(u0);
  float e1 = fast_exp2(u1);
  r0 = fast_rcp(e0 + 0.5f);
  r1 = fast_rcp(e1 + 0.5f);
}

__global__ __launch_bounds__(64) void rnn_scan(
    const float* __restrict__ x, const int* __restrict__ lengths,
    const float* __restrict__ wih, const float* __restrict__ whh,
    const float* __restrict__ bih, const float* __restrict__ bhh,
    const float* __restrict__ fcw, const float* __restrict__ fcb,
    float* __restrict__ out) {
  const int b = blockIdx.x * 64 + threadIdx.x;

  const float S = 2.885390081777926f;  // 2*log2(e)
  const float wa = whh[0], wb = whh[1], wc = whh[2], wd = whh[3];
  const float A00 = S * wa, A01 = S * wb;
  const float A10 = S * wc, A11 = S * wd;
  const float sw0 = S * wih[0];
  const float sw1 = S * wih[1];
  // sc folds: S*(b_ih + b_hh) + rowsum(A) - 1
  const float sc0 = fmaf(S, bih[0] + bhh[0], A00 + A01 - 1.0f);
  const float sc1 = fmaf(S, bih[1] + bhh[1], A10 + A11 - 1.0f);
  const float m0 = A00 + A01 - 1.0f;  // masked-step sg constant -> u = -1
  const float m1 = A10 + A11 - 1.0f;

  // sigma_max of 2x2 W_hh (exact closed form), slightly inflated for fp.
  const float g11 = wa * wa + wc * wc;
  const float g22 = wb * wb + wd * wd;
  const float g12 = wa * wb + wc * wd;
  const float half_tr = 0.5f * (g11 + g22);
  const float half_df = 0.5f * (g11 - g22);
  const float s2 = half_tr + sqrtf(half_df * half_df + g12 * g12);
  const float sigma = sqrtf(s2) * 1.0002f;

  int K;
  if (sigma > 1e-4f && sigma < 0.999f) {
    // sigma^K <= 1e-3  ->  K = ceil(ln(1e-3)/ln(sigma)); ln(1e-3) = -6.9078
    K = (int)ceilf(-6.9078f / logf(sigma));
    if (K < 8) K = 8;
  } else if (!(sigma > 1e-4f)) {
    K = 8;  // sigma ~ 0
  } else {
    K = 1 << 20;  // too close to 1: force full-scan fallback
  }
  if (!(sigma == sigma)) K = 1 << 20;  // NaN guard

  const int len = lengths[b];  // in [1, 2047]
  const float* __restrict__ xp = x + (size_t)b * T_LEN;

  float r0 = 1.0f, r1 = 1.0f;  // h = 0

  if (K <= 256) {
    // ---- fast path: uniform Kp steps, masked prefix ----
    const int Kp = (K + 15) & ~15;  // multiple of 16, <= 256
    const int t0 = len - Kp;        // may be negative

    float xs[16];
#pragma unroll
    for (int i = 0; i < 16; ++i) {
      const int t = t0 + i;
      xs[i] = xp[min(max(t, 0), T_LEN - 1)];
    }
    for (int blk = 0; blk < Kp; blk += 16) {
      float xn[16];
#pragma unroll
      for (int i = 0; i < 16; ++i) {
        const int t = t0 + blk + 16 + i;
        xn[i] = xp[min(max(t, 0), T_LEN - 1)];
      }
#pragma unroll
      for (int i = 0; i < 16; ++i) {
        const int t = t0 + blk + i;
        const bool v = t >= 0;
        const float sg0 = v ? fmaf(sw0, xs[i], sc0) : m0;  // off-chain mask
        const float sg1 = v ? fmaf(sw1, xs[i], sc1) : m1;
        rnn_step_r(sg0, sg1, A00, A01, A10, A11, r0, r1);
      }
#pragma unroll
      for (int i = 0; i < 16; ++i) xs[i] = xn[i];
    }
  } else {
    // ---- truncated exact scan (r-state form) ----
    // Start at max(0, (len-K) rounded DOWN to x32) with h = 0. Rounding
    // down only adds steps (more accurate). Error <= sqrt(2)*sigma^K.
    const int sdel = len - K;
    const int start = (sdel > 0) ? (sdel & ~31) : 0;  // multiple of 32
    const float* __restrict__ xq = xp + start;        // 16B-aligned
    const float4* __restrict__ xq4 = (const float4*)xq;
    const int L = len - start;       // steps to run, in [1, K+31] (or len)
    const int ngroups = L >> 5;
    // prefetch clamp: xq4[nb+7] must stay inside this row of 2048 floats
    const int ncap = ((T_LEN - start) >> 2) - 8;
    if (ngroups > 0) {
      float4 cur[8], nxt[8];
#pragma unroll
      for (int i = 0; i < 8; ++i) cur[i] = xq4[i];
      for (int g = 0; g < ngroups; ++g) {
        const int nb = min((g + 1) * 8, ncap);
#pragma unroll
        for (int i = 0; i < 8; ++i) nxt[i] = xq4[nb + i];
#pragma unroll
        for (int i = 0; i < 8; ++i) {
          rnn_step_r(fmaf(sw0, cur[i].x, sc0), fmaf(sw1, cur[i].x, sc1),
                     A00, A01, A10, A11, r0, r1);
          rnn_step_r(fmaf(sw0, cur[i].y, sc0), fmaf(sw1, cur[i].y, sc1),
                     A00, A01, A10, A11, r0, r1);
          rnn_step_r(fmaf(sw0, cur[i].z, sc0), fmaf(sw1, cur[i].z, sc1),
                     A00, A01, A10, A11, r0, r1);
          rnn_step_r(fmaf(sw0, cur[i].w, sc0), fmaf(sw1, cur[i].w, sc1),
                     A00, A01, A10, A11, r0, r1);
        }
#pragma unroll
        for (int i = 0; i < 8; ++i) cur[i] = nxt[i];
      }
    }
    for (int t = start + (ngroups << 5); t < len; ++t) {
      rnn_step_r(fmaf(sw0, xp[t], sc0), fmaf(sw1, xp[t], sc1),
                 A00, A01, A10, A11, r0, r1);
    }
  }

  // out = fc.(1 - r) + fcb = (fc0 + fc1 + fcb) - fc0*r0 - fc1*r1
  const float fc0 = fcw[0], fc1 = fcw[1];
  const float csum = fc0 + fc1 + fcb[0];
  out[b] = fmaf(-fc0, r0, fmaf(-fc1, r1, csum));
}

extern "C" void kernel_launch(void* const* d_in, const int* in_sizes, int n_in,
                              void* d_out, int out_size, void* d_ws,
                              size_t ws_size, hipStream_t stream) {
  const float* x = (const float*)d_in[0];
  const int* lengths = (const int*)d_in[1];
  const float* wih = (const float*)d_in[2];
  const float* whh = (const float*)d_in[3];
  const float* bih = (const float*)d_in[4];
  const float* bhh = (const float*)d_in[5];
  const float* fcw = (const float*)d_in[6];
  const float* fcb = (const float*)d_in[7];
  float* out = (float*)d_out;

  const int B = 8192;
  rnn_scan<<<B / 64, 64, 0, stream>>>(x, lengths, wih, whh, bih, bhh, fcw,
                                      fcb, out);
}